// Round 7
// baseline (535.984 us; speedup 1.0000x reference)
//
#include <hip/hip_runtime.h>

#define E_DIM 1024
#define HEADS 16
#define HD 64

typedef unsigned short ushort_t;
typedef __attribute__((ext_vector_type(8))) short bf16x8;
typedef __attribute__((ext_vector_type(4))) float floatx4;

__device__ inline unsigned int pack2bf(float a, float b) {
    unsigned int ua = __builtin_bit_cast(unsigned int, a);
    unsigned int ub = __builtin_bit_cast(unsigned int, b);
    ua = (ua + 0x8000u) >> 16;
    ub = (ub + 0x8000u) & 0xFFFF0000u;
    return ua | ub;
}
__device__ inline unsigned short f2bf(float a) {
    return (unsigned short)((__builtin_bit_cast(unsigned int, a) + 0x8000u) >> 16);
}
__device__ inline float bf2f(unsigned int s) {
    return __builtin_bit_cast(float, s << 16);
}

__device__ __forceinline__ void load_lds16(const void* g, void* l) {
    __builtin_amdgcn_global_load_lds(
        (const __attribute__((address_space(1))) unsigned int*)g,
        (__attribute__((address_space(3))) unsigned int*)l, 16, 0, 0);
}

// ---------------------------------------------------------------------------
// fp32 -> bf16 conversions
// ---------------------------------------------------------------------------
__global__ __launch_bounds__(256) void cvt_inputs(
    const float* s0, const float* s1, const float* s2,
    ushort_t* d0, ushort_t* d1, ushort_t* d2)
{
    const float* __restrict__ src = (blockIdx.y == 0) ? s0 : (blockIdx.y == 1) ? s1 : s2;
    ushort_t* __restrict__ dst = (blockIdx.y == 0) ? d0 : (blockIdx.y == 1) ? d1 : d2;
    size_t i = ((size_t)blockIdx.x * 256 + threadIdx.x) * 8;
    float4 a = *(const float4*)&src[i];
    float4 b = *(const float4*)&src[i + 4];
    uint4 o;
    o.x = pack2bf(a.x, a.y); o.y = pack2bf(a.z, a.w);
    o.z = pack2bf(b.x, b.y); o.w = pack2bf(b.z, b.w);
    *(uint4*)&dst[i] = o;
}

__global__ __launch_bounds__(256) void cvt_weights(
    const float* w0, const float* w1, const float* w2, const float* w3,
    const float* w4, const float* w5, const float* w6, const float* w7,
    ushort_t* __restrict__ out)
{
    const float* srcs[8] = {w0, w1, w2, w3, w4, w5, w6, w7};
    const float* __restrict__ src = srcs[blockIdx.y];
    ushort_t* __restrict__ dst = out + (size_t)blockIdx.y * E_DIM * E_DIM;
    size_t i = ((size_t)blockIdx.x * 256 + threadIdx.x) * 8;
    float4 a = *(const float4*)&src[i];
    float4 b = *(const float4*)&src[i + 4];
    uint4 o;
    o.x = pack2bf(a.x, a.y); o.y = pack2bf(a.z, a.w);
    o.z = pack2bf(b.x, b.y); o.w = pack2bf(b.z, b.w);
    *(uint4*)&dst[i] = o;
}

// ---------------------------------------------------------------------------
// GEMM core: 128x128 tile, BK=64, global_load_lds staging, XOR-swizzled LDS.
// LDS granule (16B) at [row][g'] holds global granule g = g' ^ (row&7):
// staging lane fetches the permuted granule (coalescing preserved within the
// 128B row); frag ds_read_b128 at g' = (kk/8 + aq) ^ (row&7) -> 2-way banks.
// ---------------------------------------------------------------------------
template<bool OUT_BF16>
__device__ __forceinline__ void gemm_core(
    const ushort_t* __restrict__ x, const ushort_t* __restrict__ W,
    const float* __restrict__ bias, void* __restrict__ outv,
    int m0, int n0, int split, int kind, float scale, int T_)
{
    __shared__ __align__(16) ushort_t As[128 * 64];
    __shared__ __align__(16) ushort_t Bs[128 * 64];

    const int tid  = threadIdx.x;
    const int lane = tid & 63;
    const int wv   = tid >> 6;
    const int rw   = (wv >> 1) * 64;
    const int cw   = (wv & 1) * 64;
    const int am   = lane & 15;
    const int aq   = lane >> 4;

    // staging: lane l covers row base+(l>>3), LDS granule (l&7);
    // fetch global granule (l&7)^((l>>3)&7)
    const int srow = lane >> 3;
    const int sg   = ((lane & 7) ^ (srow & 7)) * 8;

    floatx4 acc[4][4];
    #pragma unroll
    for (int i = 0; i < 4; ++i)
        #pragma unroll
        for (int j = 0; j < 4; ++j)
            acc[i][j] = (floatx4){0.f, 0.f, 0.f, 0.f};

    for (int k0 = 0; k0 < E_DIM; k0 += 64) {
        #pragma unroll
        for (int i = 0; i < 4; ++i) {
            int r = wv * 32 + i * 8;
            load_lds16(&x[(size_t)(m0 + r + srow) * E_DIM + k0 + sg], &As[r * 64]);
            load_lds16(&W[(size_t)(n0 + r + srow) * E_DIM + k0 + sg], &Bs[r * 64]);
        }
        __syncthreads();

        #pragma unroll
        for (int kk = 0; kk < 64; kk += 32) {
            bf16x8 af[4], bfv[4];
            #pragma unroll
            for (int i = 0; i < 4; ++i) {
                int row = rw + i * 16 + am;
                af[i] = *(const bf16x8*)&As[row * 64 + ((((kk >> 3) + aq) ^ (row & 7)) << 3)];
            }
            #pragma unroll
            for (int j = 0; j < 4; ++j) {
                int row = cw + j * 16 + am;
                bfv[j] = *(const bf16x8*)&Bs[row * 64 + ((((kk >> 3) + aq) ^ (row & 7)) << 3)];
            }
            #pragma unroll
            for (int i = 0; i < 4; ++i)
                #pragma unroll
                for (int j = 0; j < 4; ++j)
                    acc[i][j] = __builtin_amdgcn_mfma_f32_16x16x32_bf16(af[i], bfv[j], acc[i][j], 0, 0, 0);
        }
        __syncthreads();
    }

    const int cq = lane >> 4;
    const int cm = lane & 15;
    #pragma unroll
    for (int j = 0; j < 4; ++j) {
        int n = n0 + cw + j * 16 + cm;
        float bv = bias[n];
        #pragma unroll
        for (int i = 0; i < 4; ++i) {
            int mbase = m0 + rw + i * 16 + cq * 4;
            #pragma unroll
            for (int r = 0; r < 4; ++r) {
                int m = mbase + r;
                int t = m % T_;
                if (((t < split) ? 0 : 1) != kind) continue;
                float val = (acc[i][j][r] + bv) * scale;
                if (OUT_BF16) ((ushort_t*)outv)[(size_t)m * E_DIM + n] = f2bf(val);
                else          ((float*)outv)[(size_t)m * E_DIM + n] = val;
            }
        }
    }
}

// Fused Q/K/V multiway GEMMs: blockIdx.z = op*2 + kind, op in {0,1,2}
__global__ __launch_bounds__(256) void gemm_qkv(
    const ushort_t* __restrict__ xq, const ushort_t* __restrict__ xk,
    const ushort_t* __restrict__ xv, const ushort_t* __restrict__ wall,
    const float* bq_t, const float* bq_i, const float* bk_t, const float* bk_i,
    const float* bv_t, const float* bv_i,
    ushort_t* oq, ushort_t* ok, ushort_t* ov,
    const int* __restrict__ split_ptr, int T_)
{
    const int split = *split_ptr;
    const int z = blockIdx.z;
    const int op = z >> 1;
    const int kind = z & 1;
    const int m0 = blockIdx.y * 128;
    const int n0 = blockIdx.x * 128;
    const int t0 = m0 % T_;

    if (kind == 0) { if (t0 >= split) return; }
    else           { if (t0 + 128 <= split) return; }

    const ushort_t* x = (op == 0) ? xq : (op == 1) ? xk : xv;
    ushort_t* outp    = (op == 0) ? oq : (op == 1) ? ok : ov;
    const ushort_t* W = wall + (size_t)z * E_DIM * E_DIM;
    const float* bias = (op == 0) ? (kind ? bq_i : bq_t)
                      : (op == 1) ? (kind ? bk_i : bk_t)
                                  : (kind ? bv_i : bv_t);
    float scale = (op == 0) ? 0.125f : 1.0f;

    gemm_core<true>(x, W, bias, outp, m0, n0, split, kind, scale, T_);
}

// Single multiway GEMM (final projection, fp32 out)
__global__ __launch_bounds__(256) void gemm_o(
    const ushort_t* __restrict__ x, const ushort_t* __restrict__ Wt,
    const float* bt, const ushort_t* __restrict__ Wi, const float* bi,
    float* __restrict__ outp, const int* __restrict__ split_ptr, int T_)
{
    const int split = *split_ptr;
    const int kind = blockIdx.z;
    const int m0 = blockIdx.y * 128;
    const int n0 = blockIdx.x * 128;
    const int t0 = m0 % T_;

    if (kind == 0) { if (t0 >= split) return; }
    else           { if (t0 + 128 <= split) return; }

    gemm_core<false>(x, kind ? Wi : Wt, kind ? bi : bt, outp, m0, n0, split, kind, 1.0f, T_);
}

// ---------------------------------------------------------------------------
// Flash attention, bf16 MFMA. Block = 128 Q-rows of one (b,h); 4 waves, each
// handles 2 Q-subtiles of 16 rows. Q fragments loaded DIRECTLY from global
// (no Qs LDS -> 30 KB total LDS -> 4 blocks/CU). K/V/P layouts = round 5/6.
// ---------------------------------------------------------------------------
__global__ __launch_bounds__(256) void attn_mfma3(
    const ushort_t* __restrict__ q, const ushort_t* __restrict__ k,
    const ushort_t* __restrict__ v, const float* __restrict__ mask,
    ushort_t* __restrict__ outp, int T_)
{
    const int tid  = threadIdx.x;
    const int lane = tid & 63;
    const int wv   = tid >> 6;
    const int h    = blockIdx.y;
    const int b    = blockIdx.z;
    const int r0   = blockIdx.x * 128;

    __shared__ __align__(16) unsigned short Ks[2 * 64 * 40];
    __shared__ __align__(16) unsigned short Vst[2 * 64 * 40];
    __shared__ __align__(16) unsigned short Ps[4 * 2 * 16 * 40];

    const int m    = lane & 15;
    const int kq   = lane >> 4;
    const int wrow = wv * 16;

    // ---- Q fragments direct from global (one-time, 4 x 16B per lane) ----
    bf16x8 aq[2][2];
    #pragma unroll
    for (int qs = 0; qs < 2; ++qs)
        #pragma unroll
        for (int c = 0; c < 2; ++c)
            aq[qs][c] = *(const bf16x8*)&q[((size_t)(b * T_ + r0 + qs * 64 + wrow + m)) * E_DIM
                                           + h * HD + c * 32 + kq * 8];

    floatx4 oa[2][4];
    float mrun[2][4], lsum[2][4];
    #pragma unroll
    for (int qs = 0; qs < 2; ++qs)
        #pragma unroll
        for (int j = 0; j < 4; ++j) {
            oa[qs][j] = (floatx4){0.f, 0.f, 0.f, 0.f};
            mrun[qs][j] = -3.0e38f; lsum[qs][j] = 0.f;
        }

    const int vs0 = (tid >> 4) * 4;
    const int vd0 = (tid & 15) * 4;

    #pragma unroll 1
    for (int s0 = 0; s0 < T_; s0 += 64) {
        __syncthreads();

        // stage K tile
        #pragma unroll
        for (int i = 0; i < 4; ++i) {
            int f   = tid + 256 * i;
            int row = f >> 4;
            int c4  = (f & 15) * 4;
            uint2 a2 = *(const uint2*)&k[((size_t)(b * T_ + s0 + row)) * E_DIM + h * HD + c4];
            int ad = (c4 >> 5) * 2560 + row * 40 + (c4 & 31);
            *(unsigned int*)&Ks[ad]     = a2.x;
            *(unsigned int*)&Ks[ad + 2] = a2.y;
        }

        // stage V tile transposed
        {
            uint2 vvr[4];
            #pragma unroll
            for (int i = 0; i < 4; ++i)
                vvr[i] = *(const uint2*)&v[((size_t)(b * T_ + s0 + vs0 + i)) * E_DIM + h * HD + vd0];
            const ushort_t* vp = (const ushort_t*)vvr;
            int plane = (vs0 >> 5) * 2560;
            int sin   = vs0 & 31;
            #pragma unroll
            for (int t = 0; t < 4; ++t) {
                int d  = vd0 + t;
                int pr = d ^ ((d >> 4) & 3);
                uint2 w;
                w.x = (unsigned int)vp[0 * 4 + t] | ((unsigned int)vp[1 * 4 + t] << 16);
                w.y = (unsigned int)vp[2 * 4 + t] | ((unsigned int)vp[3 * 4 + t] << 16);
                *(uint2*)&Vst[plane + pr * 40 + sin] = w;
            }
        }

        __syncthreads();

        #pragma unroll
        for (int qs = 0; qs < 2; ++qs) {
            // mask prefetch for this q-subtile
            float mv[4][4];
            {
                const float* mbase = &mask[(size_t)(r0 + qs * 64 + wrow + kq * 4) * T_ + s0 + m];
                #pragma unroll
                for (int j = 0; j < 4; ++j)
                    #pragma unroll
                    for (int r = 0; r < 4; ++r)
                        mv[j][r] = mbase[r * T_ + j * 16];
            }

            // ---- QK^T ----
            floatx4 sa[4];
            #pragma unroll
            for (int j = 0; j < 4; ++j) sa[j] = (floatx4){0.f, 0.f, 0.f, 0.f};
            #pragma unroll
            for (int c = 0; c < 2; ++c) {
                #pragma unroll
                for (int j = 0; j < 4; ++j) {
                    bf16x8 bk = *(const bf16x8*)&Ks[c * 2560 + (j * 16 + m) * 40 + kq * 8];
                    sa[j] = __builtin_amdgcn_mfma_f32_16x16x32_bf16(aq[qs][c], bk, sa[j], 0, 0, 0);
                }
            }

            // ---- online softmax ----
            float mnew[4], alpha[4];
            #pragma unroll
            for (int r = 0; r < 4; ++r) {
                sa[0][r] += mv[0][r]; sa[1][r] += mv[1][r];
                sa[2][r] += mv[2][r]; sa[3][r] += mv[3][r];
                float mt = fmaxf(fmaxf(sa[0][r], sa[1][r]), fmaxf(sa[2][r], sa[3][r]));
                mt = fmaxf(mt, __shfl_xor(mt, 1));
                mt = fmaxf(mt, __shfl_xor(mt, 2));
                mt = fmaxf(mt, __shfl_xor(mt, 4));
                mt = fmaxf(mt, __shfl_xor(mt, 8));
                float mn = fmaxf(mrun[qs][r], mt);
                alpha[r] = __expf(mrun[qs][r] - mn);
                mnew[r] = mn;
                mrun[qs][r] = mn;
            }
            #pragma unroll
            for (int j = 0; j < 4; ++j)
                #pragma unroll
                for (int r = 0; r < 4; ++r)
                    oa[qs][j][r] *= alpha[r];

            float rs[4] = {0.f, 0.f, 0.f, 0.f};
            #pragma unroll
            for (int j = 0; j < 4; ++j) {
                int gl = ((((j & 1) << 1) | (m >> 3)) ^ kq) & 3;
                int pbase = wv * 1280 + (j >> 1) * 640 + (kq * 4) * 40 + gl * 8 + (m & 7);
                #pragma unroll
                for (int r = 0; r < 4; ++r) {
                    float p = __expf(sa[j][r] - mnew[r]);
                    rs[r] += p;
                    Ps[pbase + r * 40] = f2bf(p);
                }
            }
            #pragma unroll
            for (int r = 0; r < 4; ++r) {
                float s = rs[r];
                s += __shfl_xor(s, 1); s += __shfl_xor(s, 2);
                s += __shfl_xor(s, 4); s += __shfl_xor(s, 8);
                lsum[qs][r] = lsum[qs][r] * alpha[r] + s;
            }

            // ---- PV ----
            #pragma unroll
            for (int c = 0; c < 2; ++c) {
                bf16x8 ap = *(const bf16x8*)&Ps[wv * 1280 + c * 640 + m * 40 + ((kq ^ (m >> 2)) & 3) * 8];
                #pragma unroll
                for (int j = 0; j < 4; ++j) {
                    int pr = 16 * j + (m ^ j);
                    bf16x8 bv = *(const bf16x8*)&Vst[c * 2560 + pr * 40 + kq * 8];
                    oa[qs][j] = __builtin_amdgcn_mfma_f32_16x16x32_bf16(ap, bv, oa[qs][j], 0, 0, 0);
                }
            }
        }
    }

    // ---- epilogue ----
    #pragma unroll
    for (int qs = 0; qs < 2; ++qs)
        #pragma unroll
        for (int r = 0; r < 4; ++r) {
            float inv = 1.0f / lsum[qs][r];
            size_t orow = ((size_t)(b * T_ + r0 + qs * 64 + wrow + kq * 4 + r)) * E_DIM + h * HD;
            #pragma unroll
            for (int j = 0; j < 4; ++j)
                outp[orow + j * 16 + m] = f2bf(oa[qs][j][r] * inv);
        }
}

// ---------------------------------------------------------------------------
// Multiway LayerNorm, bf16 in / bf16 out, fp32 stats. One block per row.
// ---------------------------------------------------------------------------
__global__ __launch_bounds__(256) void mw_ln_bf16(
    const ushort_t* __restrict__ x,
    const float* __restrict__ gt, const float* __restrict__ bt,
    const float* __restrict__ gi, const float* __restrict__ bi,
    ushort_t* __restrict__ out,
    const int* __restrict__ split_ptr, int T_)
{
    const int split = *split_ptr;
    const int row = blockIdx.x;
    const int t = row % T_;
    const float* __restrict__ g  = (t < split) ? gt : gi;
    const float* __restrict__ bb = (t < split) ? bt : bi;

    const int tid = threadIdx.x;
    const int lane = tid & 63;
    const int wid = tid >> 6;

    __shared__ float red[8];

    uint2 xv = *(const uint2*)&x[(size_t)row * E_DIM + tid * 4];
    float f0 = bf2f(xv.x & 0xffffu), f1 = bf2f(xv.x >> 16);
    float f2 = bf2f(xv.y & 0xffffu), f3 = bf2f(xv.y >> 16);
    float s = f0 + f1 + f2 + f3;
    #pragma unroll
    for (int off = 1; off < 64; off <<= 1) s += __shfl_xor(s, off, 64);
    if (lane == 0) red[wid] = s;
    __syncthreads();
    float mu = (red[0] + red[1] + red[2] + red[3]) * (1.0f / E_DIM);

    float d0 = f0 - mu, d1 = f1 - mu, d2 = f2 - mu, d3 = f3 - mu;
    float s2 = d0*d0 + d1*d1 + d2*d2 + d3*d3;
    #pragma unroll
    for (int off = 1; off < 64; off <<= 1) s2 += __shfl_xor(s2, off, 64);
    if (lane == 0) red[4 + wid] = s2;
    __syncthreads();
    float var = (red[4] + red[5] + red[6] + red[7]) * (1.0f / E_DIM);
    float rstd = rsqrtf(var + 1e-5f);

    float4 gv = *(const float4*)&g[tid * 4];
    float4 bv = *(const float4*)&bb[tid * 4];
    uint2 ov;
    ov.x = pack2bf(d0 * rstd * gv.x + bv.x, d1 * rstd * gv.y + bv.y);
    ov.y = pack2bf(d2 * rstd * gv.z + bv.z, d3 * rstd * gv.w + bv.w);
    *(uint2*)&out[(size_t)row * E_DIM + tid * 4] = ov;
}

// ---------------------------------------------------------------------------
extern "C" void kernel_launch(void* const* d_in, const int* in_sizes, int n_in,
                              void* d_out, int out_size, void* d_ws, size_t ws_size,
                              hipStream_t stream) {
    const float* query = (const float*)d_in[0];
    const float* key   = (const float*)d_in[1];
    const float* value = (const float*)d_in[2];
    const float* mask  = (const float*)d_in[3];
    const float* Wq_t = (const float*)d_in[4];  const float* bq_t = (const float*)d_in[5];
    const float* Wq_i = (const float*)d_in[6];  const float* bq_i = (const float*)d_in[7];
    const float* Wk_t = (const float*)d_in[8];  const float* bk_t = (const float*)d_in[9];
    const float* Wk_i = (const float*)d_in[10]; const float* bk_i = (const float*)d_in[11];
    const float* Wv_t = (const float*)d_in[12]; const float* bv_t = (const float*)d_in[13];
    const float* Wv_i = (const float*)d_in[14]; const float* bv_i = (const float*)d_in[15];
    const float* Wo_t = (const float*)d_in[16]; const float* bo_t = (const float*)d_in[17];
    const float* Wo_i = (const float*)d_in[18]; const float* bo_i = (const float*)d_in[19];
    const float* ln_g_t = (const float*)d_in[20]; const float* ln_b_t = (const float*)d_in[21];
    const float* ln_g_i = (const float*)d_in[22]; const float* ln_b_i = (const float*)d_in[23];
    const int* split = (const int*)d_in[24];

    float* out = (float*)d_out;

    const int BT = in_sizes[0] / E_DIM;   // B*T = 8192
    const int T_ = 1024;
    const int B  = BT / T_;

    ushort_t* ws = (ushort_t*)d_ws;
    const size_t nx = (size_t)BT * E_DIM;        // 8M elements
    const size_t nw = (size_t)E_DIM * E_DIM;     // 1M elements
    ushort_t* xq_bf = ws;                // converted query; later LN output
    ushort_t* xk_bf = ws + nx;
    ushort_t* xv_bf = ws + 2 * nx;
    ushort_t* k_bf  = ws + 3 * nx;
    ushort_t* v_bf  = ws + 4 * nx;
    ushort_t* w_bf  = ws + 5 * nx;       // 8 weights = 8*nw = nx elements
    ushort_t* q_bf  = (ushort_t*)d_out;  // bf16 scratch inside d_out (overwritten by gemm_o)

    dim3 blk(256);
    const int cvt_blocks = (int)(nx / 2048);
    const int wcvt_blocks = (int)(nw / 2048);

    cvt_weights<<<dim3(wcvt_blocks, 8), blk, 0, stream>>>(
        Wq_t, Wq_i, Wk_t, Wk_i, Wv_t, Wv_i, Wo_t, Wo_i, w_bf);
    cvt_inputs<<<dim3(cvt_blocks, 3), blk, 0, stream>>>(
        query, key, value, xq_bf, xk_bf, xv_bf);

    gemm_qkv<<<dim3(E_DIM / 128, BT / 128, 6), blk, 0, stream>>>(
        xq_bf, xk_bf, xv_bf, w_bf,
        bq_t, bq_i, bk_t, bk_i, bv_t, bv_i,
        q_bf, k_bf, v_bf, split, T_);

    attn_mfma3<<<dim3(T_ / 128, HEADS, B), blk, 0, stream>>>(
        q_bf, k_bf, v_bf, mask, q_bf, T_);

    mw_ln_bf16<<<dim3(BT), blk, 0, stream>>>(
        q_bf, ln_g_t, ln_b_t, ln_g_i, ln_b_i, xq_bf, split, T_);

    gemm_o<<<dim3(E_DIM / 128, BT / 128, 2), blk, 0, stream>>>(
        xq_bf, w_bf + 6 * nw, bo_t, w_bf + 7 * nw, bo_i, out, split, T_);
}

// Round 8
// 499.084 us; speedup vs baseline: 1.0739x; 1.0739x over previous
//
#include <hip/hip_runtime.h>

#define E_DIM 1024
#define HEADS 16
#define HD 64

typedef unsigned short ushort_t;
typedef __attribute__((ext_vector_type(8))) short bf16x8;
typedef __attribute__((ext_vector_type(4))) float floatx4;

__device__ inline unsigned int pack2bf(float a, float b) {
    unsigned int ua = __builtin_bit_cast(unsigned int, a);
    unsigned int ub = __builtin_bit_cast(unsigned int, b);
    ua = (ua + 0x8000u) >> 16;
    ub = (ub + 0x8000u) & 0xFFFF0000u;
    return ua | ub;
}
__device__ inline unsigned short f2bf(float a) {
    return (unsigned short)((__builtin_bit_cast(unsigned int, a) + 0x8000u) >> 16);
}
__device__ inline float bf2f(unsigned int s) {
    return __builtin_bit_cast(float, s << 16);
}

__device__ __forceinline__ void load_lds16(const void* g, void* l) {
    __builtin_amdgcn_global_load_lds(
        (const __attribute__((address_space(1))) unsigned int*)g,
        (__attribute__((address_space(3))) unsigned int*)l, 16, 0, 0);
}

// ---------------------------------------------------------------------------
// fp32 -> bf16 conversions
// ---------------------------------------------------------------------------
__global__ __launch_bounds__(256) void cvt_inputs(
    const float* s0, const float* s1, const float* s2,
    ushort_t* d0, ushort_t* d1, ushort_t* d2)
{
    const float* __restrict__ src = (blockIdx.y == 0) ? s0 : (blockIdx.y == 1) ? s1 : s2;
    ushort_t* __restrict__ dst = (blockIdx.y == 0) ? d0 : (blockIdx.y == 1) ? d1 : d2;
    size_t i = ((size_t)blockIdx.x * 256 + threadIdx.x) * 8;
    float4 a = *(const float4*)&src[i];
    float4 b = *(const float4*)&src[i + 4];
    uint4 o;
    o.x = pack2bf(a.x, a.y); o.y = pack2bf(a.z, a.w);
    o.z = pack2bf(b.x, b.y); o.w = pack2bf(b.z, b.w);
    *(uint4*)&dst[i] = o;
}

__global__ __launch_bounds__(256) void cvt_weights(
    const float* w0, const float* w1, const float* w2, const float* w3,
    const float* w4, const float* w5, const float* w6, const float* w7,
    ushort_t* __restrict__ out)
{
    const float* srcs[8] = {w0, w1, w2, w3, w4, w5, w6, w7};
    const float* __restrict__ src = srcs[blockIdx.y];
    ushort_t* __restrict__ dst = out + (size_t)blockIdx.y * E_DIM * E_DIM;
    size_t i = ((size_t)blockIdx.x * 256 + threadIdx.x) * 8;
    float4 a = *(const float4*)&src[i];
    float4 b = *(const float4*)&src[i + 4];
    uint4 o;
    o.x = pack2bf(a.x, a.y); o.y = pack2bf(a.z, a.w);
    o.z = pack2bf(b.x, b.y); o.w = pack2bf(b.z, b.w);
    *(uint4*)&dst[i] = o;
}

// ---------------------------------------------------------------------------
// GEMM core: 128x128 tile, BK=32, global_load_lds staging (round-6 version,
// the best-measured variant; BK=64+swizzle regressed in round 7).
// ---------------------------------------------------------------------------
template<bool OUT_BF16>
__device__ __forceinline__ void gemm_core(
    const ushort_t* __restrict__ x, const ushort_t* __restrict__ W,
    const float* __restrict__ bias, void* __restrict__ outv,
    int m0, int n0, int split, int kind, float scale, int T_)
{
    __shared__ __align__(16) ushort_t As[128 * 32];
    __shared__ __align__(16) ushort_t Bs[128 * 32];

    const int tid  = threadIdx.x;
    const int lane = tid & 63;
    const int wv   = tid >> 6;
    const int rw   = (wv >> 1) * 64;
    const int cw   = (wv & 1) * 64;
    const int am   = lane & 15;
    const int aq   = lane >> 4;

    const int grow = wv * 32 + (lane >> 2);
    const int gcol = (lane & 3) * 8;

    floatx4 acc[4][4];
    #pragma unroll
    for (int i = 0; i < 4; ++i)
        #pragma unroll
        for (int j = 0; j < 4; ++j)
            acc[i][j] = (floatx4){0.f, 0.f, 0.f, 0.f};

    for (int k0 = 0; k0 < E_DIM; k0 += 32) {
        load_lds16(&x[(size_t)(m0 + grow) * E_DIM + k0 + gcol],      &As[(wv * 32) * 32]);
        load_lds16(&x[(size_t)(m0 + grow + 16) * E_DIM + k0 + gcol], &As[(wv * 32 + 16) * 32]);
        load_lds16(&W[(size_t)(n0 + grow) * E_DIM + k0 + gcol],      &Bs[(wv * 32) * 32]);
        load_lds16(&W[(size_t)(n0 + grow + 16) * E_DIM + k0 + gcol], &Bs[(wv * 32 + 16) * 32]);
        __syncthreads();

        bf16x8 af[4], bfv[4];
        #pragma unroll
        for (int i = 0; i < 4; ++i)
            af[i] = *(const bf16x8*)&As[(rw + i * 16 + am) * 32 + aq * 8];
        #pragma unroll
        for (int j = 0; j < 4; ++j)
            bfv[j] = *(const bf16x8*)&Bs[(cw + j * 16 + am) * 32 + aq * 8];

        #pragma unroll
        for (int i = 0; i < 4; ++i)
            #pragma unroll
            for (int j = 0; j < 4; ++j)
                acc[i][j] = __builtin_amdgcn_mfma_f32_16x16x32_bf16(af[i], bfv[j], acc[i][j], 0, 0, 0);
        __syncthreads();
    }

    const int cq = lane >> 4;
    const int cm = lane & 15;
    #pragma unroll
    for (int j = 0; j < 4; ++j) {
        int n = n0 + cw + j * 16 + cm;
        float bv = bias[n];
        #pragma unroll
        for (int i = 0; i < 4; ++i) {
            int mbase = m0 + rw + i * 16 + cq * 4;
            #pragma unroll
            for (int r = 0; r < 4; ++r) {
                int m = mbase + r;
                int t = m % T_;
                if (((t < split) ? 0 : 1) != kind) continue;
                float val = (acc[i][j][r] + bv) * scale;
                if (OUT_BF16) ((ushort_t*)outv)[(size_t)m * E_DIM + n] = f2bf(val);
                else          ((float*)outv)[(size_t)m * E_DIM + n] = val;
            }
        }
    }
}

// Fused Q/K/V multiway GEMMs: blockIdx.z = op*2 + kind, op in {0,1,2}
__global__ __launch_bounds__(256) void gemm_qkv(
    const ushort_t* __restrict__ xq, const ushort_t* __restrict__ xk,
    const ushort_t* __restrict__ xv, const ushort_t* __restrict__ wall,
    const float* bq_t, const float* bq_i, const float* bk_t, const float* bk_i,
    const float* bv_t, const float* bv_i,
    ushort_t* oq, ushort_t* ok, ushort_t* ov,
    const int* __restrict__ split_ptr, int T_)
{
    const int split = *split_ptr;
    const int z = blockIdx.z;
    const int op = z >> 1;
    const int kind = z & 1;
    const int m0 = blockIdx.y * 128;
    const int n0 = blockIdx.x * 128;
    const int t0 = m0 % T_;

    if (kind == 0) { if (t0 >= split) return; }
    else           { if (t0 + 128 <= split) return; }

    const ushort_t* x = (op == 0) ? xq : (op == 1) ? xk : xv;
    ushort_t* outp    = (op == 0) ? oq : (op == 1) ? ok : ov;
    const ushort_t* W = wall + (size_t)z * E_DIM * E_DIM;
    const float* bias = (op == 0) ? (kind ? bq_i : bq_t)
                      : (op == 1) ? (kind ? bk_i : bk_t)
                                  : (kind ? bv_i : bv_t);
    float scale = (op == 0) ? 0.125f : 1.0f;

    gemm_core<true>(x, W, bias, outp, m0, n0, split, kind, scale, T_);
}

// Single multiway GEMM (final projection, fp32 out)
__global__ __launch_bounds__(256) void gemm_o(
    const ushort_t* __restrict__ x, const ushort_t* __restrict__ Wt,
    const float* bt, const ushort_t* __restrict__ Wi, const float* bi,
    float* __restrict__ outp, const int* __restrict__ split_ptr, int T_)
{
    const int split = *split_ptr;
    const int kind = blockIdx.z;
    const int m0 = blockIdx.y * 128;
    const int n0 = blockIdx.x * 128;
    const int t0 = m0 % T_;

    if (kind == 0) { if (t0 >= split) return; }
    else           { if (t0 + 128 <= split) return; }

    gemm_core<false>(x, kind ? Wi : Wt, kind ? bi : bt, outp, m0, n0, split, kind, 1.0f, T_);
}

// ---------------------------------------------------------------------------
// Flash attention, bf16 MFMA with DOUBLE-BUFFERED K/V and one barrier/tile.
// Block = 128 Q-rows of one (b,h); 4 waves x 2 Q-subtiles. Per tile: issue
// next tile's global loads (regs), compute from buf[cur], store regs into
// buf[nxt], barrier. Q frags direct from global. Layouts = rounds 5-7.
// ---------------------------------------------------------------------------
__global__ __launch_bounds__(256) void attn_mfma4(
    const ushort_t* __restrict__ q, const ushort_t* __restrict__ k,
    const ushort_t* __restrict__ v, const float* __restrict__ mask,
    ushort_t* __restrict__ outp, int T_)
{
    const int tid  = threadIdx.x;
    const int lane = tid & 63;
    const int wv   = tid >> 6;
    const int h    = blockIdx.y;
    const int b    = blockIdx.z;
    const int r0   = blockIdx.x * 128;

    __shared__ __align__(16) unsigned short Ks[2 * 5120];   // [buf][plane*2560+row*40+col]
    __shared__ __align__(16) unsigned short Vst[2 * 5120];
    __shared__ __align__(16) unsigned short Ps[4 * 1280];

    const int m    = lane & 15;
    const int kq   = lane >> 4;
    const int wrow = wv * 16;

    // ---- Q fragments direct from global ----
    bf16x8 aq[2][2];
    #pragma unroll
    for (int qs = 0; qs < 2; ++qs)
        #pragma unroll
        for (int c = 0; c < 2; ++c)
            aq[qs][c] = *(const bf16x8*)&q[((size_t)(b * T_ + r0 + qs * 64 + wrow + m)) * E_DIM
                                           + h * HD + c * 32 + kq * 8];

    floatx4 oa[2][4];
    float mrun[2][4], lsum[2][4];
    #pragma unroll
    for (int qs = 0; qs < 2; ++qs)
        #pragma unroll
        for (int j = 0; j < 4; ++j) {
            oa[qs][j] = (floatx4){0.f, 0.f, 0.f, 0.f};
            mrun[qs][j] = -3.0e38f; lsum[qs][j] = 0.f;
        }

    // staging coords
    const int krow = tid >> 4;              // K: rows 0..15 (+16i), c4 = (tid&15)*4
    const int kc4  = (tid & 15) * 4;
    const int kad  = (kc4 >> 5) * 2560 + krow * 40 + (kc4 & 31);
    const int vs0  = (tid >> 4) * 4;
    const int vd0  = (tid & 15) * 4;
    const int vplane = (vs0 >> 5) * 2560;
    const int vsin   = vs0 & 31;

    uint2 kreg[4], vreg[4];

    // ---- prologue: load tile 0 and store to buf 0 ----
    #pragma unroll
    for (int i = 0; i < 4; ++i)
        kreg[i] = *(const uint2*)&k[((size_t)(b * T_ + krow + 16 * i)) * E_DIM + h * HD + kc4];
    #pragma unroll
    for (int i = 0; i < 4; ++i)
        vreg[i] = *(const uint2*)&v[((size_t)(b * T_ + vs0 + i)) * E_DIM + h * HD + vd0];

    #pragma unroll
    for (int i = 0; i < 4; ++i) {
        int ad = kad + 16 * i * 40;
        *(unsigned int*)&Ks[ad]     = kreg[i].x;
        *(unsigned int*)&Ks[ad + 2] = kreg[i].y;
    }
    {
        const ushort_t* vp = (const ushort_t*)vreg;
        #pragma unroll
        for (int t = 0; t < 4; ++t) {
            int d  = vd0 + t;
            int pr = d ^ ((d >> 4) & 3);
            uint2 w;
            w.x = (unsigned int)vp[0 * 4 + t] | ((unsigned int)vp[1 * 4 + t] << 16);
            w.y = (unsigned int)vp[2 * 4 + t] | ((unsigned int)vp[3 * 4 + t] << 16);
            *(uint2*)&Vst[vplane + pr * 40 + vsin] = w;
        }
    }
    __syncthreads();

    const int NT = T_ / 64;
    #pragma unroll 1
    for (int it = 0; it < NT; ++it) {
        const int cur = (it & 1) * 5120;
        const int nxt = ((it + 1) & 1) * 5120;
        const int s0 = it * 64;

        // ---- issue next tile's global loads (latency overlaps compute) ----
        if (it + 1 < NT) {
            int s0n = s0 + 64;
            #pragma unroll
            for (int i = 0; i < 4; ++i)
                kreg[i] = *(const uint2*)&k[((size_t)(b * T_ + s0n + krow + 16 * i)) * E_DIM + h * HD + kc4];
            #pragma unroll
            for (int i = 0; i < 4; ++i)
                vreg[i] = *(const uint2*)&v[((size_t)(b * T_ + s0n + vs0 + i)) * E_DIM + h * HD + vd0];
        }

        // ---- compute from buf[cur] ----
        #pragma unroll
        for (int qs = 0; qs < 2; ++qs) {
            float mv[4][4];
            {
                const float* mbase = &mask[(size_t)(r0 + qs * 64 + wrow + kq * 4) * T_ + s0 + m];
                #pragma unroll
                for (int j = 0; j < 4; ++j)
                    #pragma unroll
                    for (int r = 0; r < 4; ++r)
                        mv[j][r] = mbase[r * T_ + j * 16];
            }

            floatx4 sa[4];
            #pragma unroll
            for (int j = 0; j < 4; ++j) sa[j] = (floatx4){0.f, 0.f, 0.f, 0.f};
            #pragma unroll
            for (int c = 0; c < 2; ++c) {
                #pragma unroll
                for (int j = 0; j < 4; ++j) {
                    bf16x8 bk = *(const bf16x8*)&Ks[cur + c * 2560 + (j * 16 + m) * 40 + kq * 8];
                    sa[j] = __builtin_amdgcn_mfma_f32_16x16x32_bf16(aq[qs][c], bk, sa[j], 0, 0, 0);
                }
            }

            float mnew[4], alpha[4];
            #pragma unroll
            for (int r = 0; r < 4; ++r) {
                sa[0][r] += mv[0][r]; sa[1][r] += mv[1][r];
                sa[2][r] += mv[2][r]; sa[3][r] += mv[3][r];
                float mt = fmaxf(fmaxf(sa[0][r], sa[1][r]), fmaxf(sa[2][r], sa[3][r]));
                mt = fmaxf(mt, __shfl_xor(mt, 1));
                mt = fmaxf(mt, __shfl_xor(mt, 2));
                mt = fmaxf(mt, __shfl_xor(mt, 4));
                mt = fmaxf(mt, __shfl_xor(mt, 8));
                float mn = fmaxf(mrun[qs][r], mt);
                alpha[r] = __expf(mrun[qs][r] - mn);
                mnew[r] = mn;
                mrun[qs][r] = mn;
            }
            #pragma unroll
            for (int j = 0; j < 4; ++j)
                #pragma unroll
                for (int r = 0; r < 4; ++r)
                    oa[qs][j][r] *= alpha[r];

            float rs[4] = {0.f, 0.f, 0.f, 0.f};
            #pragma unroll
            for (int j = 0; j < 4; ++j) {
                int gl = ((((j & 1) << 1) | (m >> 3)) ^ kq) & 3;
                int pbase = wv * 1280 + (j >> 1) * 640 + (kq * 4) * 40 + gl * 8 + (m & 7);
                #pragma unroll
                for (int r = 0; r < 4; ++r) {
                    float p = __expf(sa[j][r] - mnew[r]);
                    rs[r] += p;
                    Ps[pbase + r * 40] = f2bf(p);
                }
            }
            #pragma unroll
            for (int r = 0; r < 4; ++r) {
                float s = rs[r];
                s += __shfl_xor(s, 1); s += __shfl_xor(s, 2);
                s += __shfl_xor(s, 4); s += __shfl_xor(s, 8);
                lsum[qs][r] = lsum[qs][r] * alpha[r] + s;
            }

            #pragma unroll
            for (int c = 0; c < 2; ++c) {
                bf16x8 ap = *(const bf16x8*)&Ps[wv * 1280 + c * 640 + m * 40 + ((kq ^ (m >> 2)) & 3) * 8];
                #pragma unroll
                for (int j = 0; j < 4; ++j) {
                    int pr = 16 * j + (m ^ j);
                    bf16x8 bv = *(const bf16x8*)&Vst[cur + c * 2560 + pr * 40 + kq * 8];
                    oa[qs][j] = __builtin_amdgcn_mfma_f32_16x16x32_bf16(ap, bv, oa[qs][j], 0, 0, 0);
                }
            }
        }

        // ---- store next tile into buf[nxt], then single barrier ----
        if (it + 1 < NT) {
            #pragma unroll
            for (int i = 0; i < 4; ++i) {
                int ad = nxt + kad + 16 * i * 40;
                *(unsigned int*)&Ks[ad]     = kreg[i].x;
                *(unsigned int*)&Ks[ad + 2] = kreg[i].y;
            }
            const ushort_t* vp = (const ushort_t*)vreg;
            #pragma unroll
            for (int t = 0; t < 4; ++t) {
                int d  = vd0 + t;
                int pr = d ^ ((d >> 4) & 3);
                uint2 w;
                w.x = (unsigned int)vp[0 * 4 + t] | ((unsigned int)vp[1 * 4 + t] << 16);
                w.y = (unsigned int)vp[2 * 4 + t] | ((unsigned int)vp[3 * 4 + t] << 16);
                *(uint2*)&Vst[nxt + vplane + pr * 40 + vsin] = w;
            }
            __syncthreads();
        }
    }

    // ---- epilogue ----
    #pragma unroll
    for (int qs = 0; qs < 2; ++qs)
        #pragma unroll
        for (int r = 0; r < 4; ++r) {
            float inv = 1.0f / lsum[qs][r];
            size_t orow = ((size_t)(b * T_ + r0 + qs * 64 + wrow + kq * 4 + r)) * E_DIM + h * HD;
            #pragma unroll
            for (int j = 0; j < 4; ++j)
                outp[orow + j * 16 + m] = f2bf(oa[qs][j][r] * inv);
        }
}

// ---------------------------------------------------------------------------
// Multiway LayerNorm, bf16 in / bf16 out, fp32 stats. One block per row.
// ---------------------------------------------------------------------------
__global__ __launch_bounds__(256) void mw_ln_bf16(
    const ushort_t* __restrict__ x,
    const float* __restrict__ gt, const float* __restrict__ bt,
    const float* __restrict__ gi, const float* __restrict__ bi,
    ushort_t* __restrict__ out,
    const int* __restrict__ split_ptr, int T_)
{
    const int split = *split_ptr;
    const int row = blockIdx.x;
    const int t = row % T_;
    const float* __restrict__ g  = (t < split) ? gt : gi;
    const float* __restrict__ bb = (t < split) ? bt : bi;

    const int tid = threadIdx.x;
    const int lane = tid & 63;
    const int wid = tid >> 6;

    __shared__ float red[8];

    uint2 xv = *(const uint2*)&x[(size_t)row * E_DIM + tid * 4];
    float f0 = bf2f(xv.x & 0xffffu), f1 = bf2f(xv.x >> 16);
    float f2 = bf2f(xv.y & 0xffffu), f3 = bf2f(xv.y >> 16);
    float s = f0 + f1 + f2 + f3;
    #pragma unroll
    for (int off = 1; off < 64; off <<= 1) s += __shfl_xor(s, off, 64);
    if (lane == 0) red[wid] = s;
    __syncthreads();
    float mu = (red[0] + red[1] + red[2] + red[3]) * (1.0f / E_DIM);

    float d0 = f0 - mu, d1 = f1 - mu, d2 = f2 - mu, d3 = f3 - mu;
    float s2 = d0*d0 + d1*d1 + d2*d2 + d3*d3;
    #pragma unroll
    for (int off = 1; off < 64; off <<= 1) s2 += __shfl_xor(s2, off, 64);
    if (lane == 0) red[4 + wid] = s2;
    __syncthreads();
    float var = (red[4] + red[5] + red[6] + red[7]) * (1.0f / E_DIM);
    float rstd = rsqrtf(var + 1e-5f);

    float4 gv = *(const float4*)&g[tid * 4];
    float4 bv = *(const float4*)&bb[tid * 4];
    uint2 ov;
    ov.x = pack2bf(d0 * rstd * gv.x + bv.x, d1 * rstd * gv.y + bv.y);
    ov.y = pack2bf(d2 * rstd * gv.z + bv.z, d3 * rstd * gv.w + bv.w);
    *(uint2*)&out[(size_t)row * E_DIM + tid * 4] = ov;
}

// ---------------------------------------------------------------------------
extern "C" void kernel_launch(void* const* d_in, const int* in_sizes, int n_in,
                              void* d_out, int out_size, void* d_ws, size_t ws_size,
                              hipStream_t stream) {
    const float* query = (const float*)d_in[0];
    const float* key   = (const float*)d_in[1];
    const float* value = (const float*)d_in[2];
    const float* mask  = (const float*)d_in[3];
    const float* Wq_t = (const float*)d_in[4];  const float* bq_t = (const float*)d_in[5];
    const float* Wq_i = (const float*)d_in[6];  const float* bq_i = (const float*)d_in[7];
    const float* Wk_t = (const float*)d_in[8];  const float* bk_t = (const float*)d_in[9];
    const float* Wk_i = (const float*)d_in[10]; const float* bk_i = (const float*)d_in[11];
    const float* Wv_t = (const float*)d_in[12]; const float* bv_t = (const float*)d_in[13];
    const float* Wv_i = (const float*)d_in[14]; const float* bv_i = (const float*)d_in[15];
    const float* Wo_t = (const float*)d_in[16]; const float* bo_t = (const float*)d_in[17];
    const float* Wo_i = (const float*)d_in[18]; const float* bo_i = (const float*)d_in[19];
    const float* ln_g_t = (const float*)d_in[20]; const float* ln_b_t = (const float*)d_in[21];
    const float* ln_g_i = (const float*)d_in[22]; const float* ln_b_i = (const float*)d_in[23];
    const int* split = (const int*)d_in[24];

    float* out = (float*)d_out;

    const int BT = in_sizes[0] / E_DIM;   // B*T = 8192
    const int T_ = 1024;
    const int B  = BT / T_;

    ushort_t* ws = (ushort_t*)d_ws;
    const size_t nx = (size_t)BT * E_DIM;        // 8M elements
    const size_t nw = (size_t)E_DIM * E_DIM;     // 1M elements
    ushort_t* xq_bf = ws;                // converted query; later LN output
    ushort_t* xk_bf = ws + nx;
    ushort_t* xv_bf = ws + 2 * nx;
    ushort_t* k_bf  = ws + 3 * nx;
    ushort_t* v_bf  = ws + 4 * nx;
    ushort_t* w_bf  = ws + 5 * nx;       // 8 weights = 8*nw = nx elements
    ushort_t* q_bf  = (ushort_t*)d_out;  // bf16 scratch inside d_out (overwritten by gemm_o)

    dim3 blk(256);
    const int cvt_blocks = (int)(nx / 2048);
    const int wcvt_blocks = (int)(nw / 2048);

    cvt_weights<<<dim3(wcvt_blocks, 8), blk, 0, stream>>>(
        Wq_t, Wq_i, Wk_t, Wk_i, Wv_t, Wv_i, Wo_t, Wo_i, w_bf);
    cvt_inputs<<<dim3(cvt_blocks, 3), blk, 0, stream>>>(
        query, key, value, xq_bf, xk_bf, xv_bf);

    gemm_qkv<<<dim3(E_DIM / 128, BT / 128, 6), blk, 0, stream>>>(
        xq_bf, xk_bf, xv_bf, w_bf,
        bq_t, bq_i, bk_t, bk_i, bv_t, bv_i,
        q_bf, k_bf, v_bf, split, T_);

    attn_mfma4<<<dim3(T_ / 128, HEADS, B), blk, 0, stream>>>(
        q_bf, k_bf, v_bf, mask, q_bf, T_);

    mw_ln_bf16<<<dim3(BT), blk, 0, stream>>>(
        q_bf, ln_g_t, ln_b_t, ln_g_i, ln_b_i, xq_bf, split, T_);

    gemm_o<<<dim3(E_DIM / 128, BT / 128, 2), blk, 0, stream>>>(
        xq_bf, w_bf + 6 * nw, bo_t, w_bf + 7 * nw, bo_i, out, split, T_);
}